// Round 15
// baseline (418.112 us; speedup 1.0000x reference)
//
#include <hip/hip_runtime.h>
#include <hip/hip_bf16.h>

typedef __attribute__((ext_vector_type(8))) __bf16 bf16x8;
typedef __attribute__((ext_vector_type(4))) float f32x4;
typedef __attribute__((ext_vector_type(4))) unsigned short ushort4v;
typedef __attribute__((ext_vector_type(8))) unsigned short ushort8v;
typedef unsigned short u16;

// ---------- helpers ----------
__device__ __forceinline__ u16 f2bf_bits(float f) {
    union { float f; unsigned int u; } x; x.f = f;
    unsigned int r = x.u + 0x7FFFu + ((x.u >> 16) & 1u);   // RNE
    return (u16)(r >> 16);
}

__device__ __forceinline__ float bf2f(u16 u) {
    union { unsigned int i; float f; } x; x.i = ((unsigned)u) << 16; return x.f;
}

__device__ __forceinline__ void gload_lds16(const void* g, void* l) {
    __builtin_amdgcn_global_load_lds(
        (const __attribute__((address_space(1))) void*)g,
        (__attribute__((address_space(3))) void*)l, 16, 0, 0);
}

#define BARRIER()  __builtin_amdgcn_s_barrier()
#define LGKM0()    asm volatile("s_waitcnt lgkmcnt(0)" ::: "memory")
#define VMW8()     asm volatile("s_waitcnt vmcnt(8)" ::: "memory")
#define VMW2()     asm volatile("s_waitcnt vmcnt(2)" ::: "memory")
#define SGB_DS(n)   __builtin_amdgcn_sched_group_barrier(0x100, n, 0)
#define SGB_MFMA(n) __builtin_amdgcn_sched_group_barrier(0x8, n, 0)

// ---------- fused preprocessing: x cvt + 4 weight transpose-cvts ----------
__global__ __launch_bounds__(256)
void prep(const float* __restrict__ x,   u16* __restrict__ xb,
          const float* __restrict__ We1, u16* __restrict__ w1t,
          const float* __restrict__ We2, u16* __restrict__ w2t,
          const float* __restrict__ Wd1, u16* __restrict__ w3t,
          const float* __restrict__ Wd2, u16* __restrict__ w4t) {
    int bid = blockIdx.x;

    if (bid >= 9728) {                       // ---- cvt region: x -> xb (16M elems)
        const int i = ((bid - 9728) << 10) + ((int)threadIdx.x << 2);
        f32x4 v = *reinterpret_cast<const f32x4*>(x + i);
        ushort4v o;
        o.x = f2bf_bits(v.x); o.y = f2bf_bits(v.y);
        o.z = f2bf_bits(v.z); o.w = f2bf_bits(v.w);
        *reinterpret_cast<ushort4v*>(xb + i) = o;
        return;
    }

    const float* in; u16* out; int R, C, bx, by;
    if (bid < 4096)      { in = We1; out = w1t; R = 4096; C = 4096; bx = bid & 63; by = bid >> 6; }
    else if (bid < 5120) { bid -= 4096; in = We2; out = w2t; R = 4096; C = 1024; bx = bid & 15; by = bid >> 4; }
    else if (bid < 5632) { bid -= 5120; in = Wd1; out = w3t; R = 512;  C = 4096; bx = bid & 63; by = bid >> 6; }
    else                 { bid -= 5632; in = Wd2; out = w4t; R = 4096; C = 4096; bx = bid & 63; by = bid >> 6; }

    __shared__ float t[64][67];
    const int c0 = bx << 6;
    const int r0 = by << 6;
    const int tx = threadIdx.x & 15;
    const int ty = threadIdx.x >> 4;
    #pragma unroll
    for (int j = 0; j < 4; ++j) {
        f32x4 v = *reinterpret_cast<const f32x4*>(
            &in[(size_t)(r0 + ty + 16 * j) * C + c0 + (tx << 2)]);
        *reinterpret_cast<f32x4*>(&t[ty + 16 * j][tx << 2]) = v;
    }
    __syncthreads();
    const int orow8 = threadIdx.x >> 3;
    const int seg8  = (threadIdx.x & 7) << 3;
    #pragma unroll
    for (int p = 0; p < 2; ++p) {
        const int oc = orow8 + (p << 5);
        ushort8v o;
        #pragma unroll
        for (int i = 0; i < 8; ++i)
            o[i] = f2bf_bits(t[seg8 + i][oc]);
        *reinterpret_cast<ushort8v*>(&out[(size_t)(c0 + oc) * R + r0 + seg8]) = o;
    }
}

// ---------- split-K reduce (bf16 partials) + bias + reparameterization ----------
__global__ __launch_bounds__(256)
void zred(const u16* __restrict__ P, const float* __restrict__ be2,
          const float* __restrict__ eps, float* __restrict__ mu,
          float* __restrict__ lv, u16* __restrict__ zs) {
    const int i = blockIdx.x * 256 + threadIdx.x;      // over 4096*512/4
    const int r = i >> 7;
    const int c4 = (i & 127) << 2;
    const size_t base = (size_t)r * 1024 + c4;
    const size_t PS = (size_t)4096 * 1024;

    f32x4 m = (f32x4)(0.0f);
    f32x4 l = (f32x4)(0.0f);
    #pragma unroll
    for (int s = 0; s < 4; ++s) {
        ushort4v pm = *reinterpret_cast<const ushort4v*>(P + s * PS + base);
        ushort4v pl = *reinterpret_cast<const ushort4v*>(P + s * PS + base + 512);
        m.x += bf2f(pm.x); m.y += bf2f(pm.y); m.z += bf2f(pm.z); m.w += bf2f(pm.w);
        l.x += bf2f(pl.x); l.y += bf2f(pl.y); l.z += bf2f(pl.z); l.w += bf2f(pl.w);
    }
    m += *reinterpret_cast<const f32x4*>(be2 + c4);
    l += *reinterpret_cast<const f32x4*>(be2 + 512 + c4);

    const size_t ob = (size_t)r * 512 + c4;
    *reinterpret_cast<f32x4*>(mu + ob) = m;
    *reinterpret_cast<f32x4*>(lv + ob) = l;

    f32x4 e = *reinterpret_cast<const f32x4*>(eps + ob);
    ushort4v o;
    o.x = f2bf_bits(m.x + __expf(0.5f * l.x) * e.x);
    o.y = f2bf_bits(m.y + __expf(0.5f * l.y) * e.y);
    o.z = f2bf_bits(m.z + __expf(0.5f * l.z) * e.z);
    o.w = f2bf_bits(m.w + __expf(0.5f * l.w) * e.w);
    *reinterpret_cast<ushort4v*>(zs + ob) = o;
}

// ---------- 256x256 8-phase GEMM, reads-at-phase-start (WAR-free frags) ----------
// Frag double-buffer: aa0/aa1 = A g0/g1 (time-multiplexed across bufs),
// b0A/b0B, b1A/b1B = B halves per buf. Every phase's reads target frags dead
// >=1 phase and untouched by the phase's MM -> reads issue BEFORE the MFMA
// cluster (SGB-pinned: DS_READ n, then MFMA 16) and complete under its drain.
// Stage regions still >=2 barriers after last read-issue (r9 invariant).
// Drains: vmcnt(2) at ph2 (prev-iter buf1 stages) and ph6 (this-iter buf0).
// MODE 0: relu->bf16. MODE 1: f32. MODE 3: split-K bf16 partial, no bias.
template<int MODE>
__global__ __launch_bounds__(512, 2)
void gemm256(const u16* __restrict__ A, const u16* __restrict__ Bt,
             const float* __restrict__ bias,
             u16* __restrict__ obf, float* __restrict__ of32,
             int M, int N, int K, int ntiles)
{
    extern __shared__ char lds[];
    const int tid  = threadIdx.x;
    const int lane = tid & 63;
    const int w    = tid >> 6;
    const int wr   = w >> 2;
    const int wc   = w & 3;

    int bid = blockIdx.x;
    int sid = 0;
    int nwg = gridDim.x;
    if (MODE == 3) { sid = bid & 3; bid >>= 2; nwg >>= 2; }
    const int cpx = nwg >> 3;
    bid = (bid & 7) * cpx + (bid >> 3);
    const int nbx  = N >> 8;
    const int brow = (bid / nbx) << 8;
    const int bcol = (bid % nbx) << 8;
    const int kbase = (MODE == 3) ? sid * ntiles : 0;
    u16* pp = (MODE == 3) ? obf + (size_t)sid * M * N : obf;

    const int srow  = tid >> 3;
    const int scole = (((tid & 7) ^ (srow & 7)) << 4) >> 1;
    const size_t aoff = (size_t)(brow + srow) * K + scole;
    const size_t boff = (size_t)(bcol + srow) * K + scole;
    const size_t rowK64 = (size_t)64 * K;
    const int wave1024 = w << 10;

    const int lo16 = (lane >> 4) << 4;
    const int swzm = (lane & 7) << 4;
    const int low0 = lo16 ^ swzm;
    const int low1 = (64 | lo16) ^ swzm;
    const int rA   = (lane & 15) << 7;
    const int rB   = ((((wc & 1) << 6) | (lane & 15)) << 7);
    const int regA = wr << 14;
    const int regB = 32768 + ((wc >> 1) << 14);

    bf16x8 aa0[4][2], aa1[4][2];        // A g0 / g1
    bf16x8 b0A[2][2], b0B[2][2];        // B n0-1 per buf
    bf16x8 b1A[2][2], b1B[2][2];        // B n2-3 per buf
    f32x4 acc[8][4];
    #pragma unroll
    for (int m = 0; m < 8; ++m)
        #pragma unroll
        for (int n = 0; n < 4; ++n)
            acc[m][n] = (f32x4)(0.0f);

#define STAGE_A(buf, h, kt) do { \
    const u16* _s = A + aoff + (size_t)(h) * 128 * K + (size_t)(kt) * 64; \
    gload_lds16(_s,          lds + ((buf) << 16) + ((h) << 14) + wave1024); \
    gload_lds16(_s + rowK64, lds + ((buf) << 16) + ((h) << 14) + 8192 + wave1024); \
} while (0)

#define STAGE_B(buf, h, kt) do { \
    const u16* _s = Bt + boff + (size_t)(h) * 128 * K + (size_t)(kt) * 64; \
    gload_lds16(_s,          lds + ((buf) << 16) + 32768 + ((h) << 14) + wave1024); \
    gload_lds16(_s + rowK64, lds + ((buf) << 16) + 32768 + ((h) << 14) + 8192 + wave1024); \
} while (0)

#define READ_AF(dst, buf, g) do { \
    _Pragma("unroll") \
    for (int m = 0; m < 4; ++m) { \
        const int _b = ((buf) << 16) + regA + rA + ((((g) << 2) + m) << 11); \
        dst[m][0] = *reinterpret_cast<const bf16x8*>(lds + _b + low0); \
        dst[m][1] = *reinterpret_cast<const bf16x8*>(lds + _b + low1); \
    } \
} while (0)

#define READ_BF(dst, buf, half) do { \
    _Pragma("unroll") \
    for (int n = 0; n < 2; ++n) { \
        const int _b = ((buf) << 16) + regB + rB + ((((half) << 1) + n) << 11); \
        dst[n][0] = *reinterpret_cast<const bf16x8*>(lds + _b + low0); \
        dst[n][1] = *reinterpret_cast<const bf16x8*>(lds + _b + low1); \
    } \
} while (0)

#define MM_F(af, bf, mb, nb) do { \
    __builtin_amdgcn_s_setprio(1); \
    _Pragma("unroll") \
    for (int m = 0; m < 4; ++m) \
        _Pragma("unroll") \
        for (int n = 0; n < 2; ++n) \
            _Pragma("unroll") \
            for (int s = 0; s < 2; ++s) \
                acc[(mb) + m][(nb) + n] = __builtin_amdgcn_mfma_f32_16x16x32_bf16( \
                    af[m][s], bf[n][s], acc[(mb) + m][(nb) + n], 0, 0, 0); \
    __builtin_amdgcn_s_setprio(0); \
} while (0)

    const int NIT = ntiles >> 1;   // 2 K-tiles of 64 per iteration

    // ---- prologue: tile kbase -> buf0 (8), kbase+1 -> buf1 (8) ----
    STAGE_A(0, 0, kbase); STAGE_A(0, 1, kbase); STAGE_B(0, 0, kbase); STAGE_B(0, 1, kbase);
    STAGE_A(1, 0, kbase + 1); STAGE_A(1, 1, kbase + 1); STAGE_B(1, 0, kbase + 1); STAGE_B(1, 1, kbase + 1);
    VMW8(); BARRIER();
    READ_AF(aa0, 0, 0); READ_BF(b0A, 0, 0);    // ph1 operands (buf0 drained)

    for (int it = 0; it < NIT; ++it) {
        const int tn0r = 2 * it + 2;
        const int tn1r = 2 * it + 3;
        const int tn0 = kbase + (tn0r < ntiles ? tn0r : ntiles - 1);  // dead-stage clamp
        const int tn1 = kbase + (tn1r < ntiles ? tn1r : ntiles - 1);

        // ph1: read buf0.B1 (dead since prev ph3-consume); MM g0 x B0
        BARRIER(); LGKM0();
        SGB_DS(4); SGB_MFMA(16);
        READ_BF(b1A, 0, 1);
        MM_F(aa0, b0A, 0, 0);

        // ph2: read buf0.g1; stage buf0.B0<-tn0; MM g0 x B1; drain prev buf1 stages
        BARRIER(); LGKM0();
        SGB_DS(8); SGB_MFMA(16);
        READ_AF(aa1, 0, 1);
        STAGE_B(0, 0, tn0);
        MM_F(aa0, b1A, 0, 2);
        VMW2();

        // ph3: read buf1.g0 (drained ph2); stage buf0.B1<-tn0; MM g1 x B1
        BARRIER(); LGKM0();
        SGB_DS(8); SGB_MFMA(16);
        READ_AF(aa0, 1, 0);
        STAGE_B(0, 1, tn0);
        MM_F(aa1, b1A, 4, 2);

        // ph4: read buf1.B0; stage buf0.A<-tn0; MM g1 x B0
        BARRIER(); LGKM0();
        SGB_DS(4); SGB_MFMA(16);
        READ_BF(b0B, 1, 0);
        STAGE_A(0, 0, tn0); STAGE_A(0, 1, tn0);
        MM_F(aa1, b0A, 4, 0);

        // ph5: read buf1.B1; MM g0' x B0'
        BARRIER(); LGKM0();
        SGB_DS(4); SGB_MFMA(16);
        READ_BF(b1B, 1, 1);
        MM_F(aa0, b0B, 0, 0);

        // ph6: read buf1.g1; stage buf1.B0<-tn1; MM g0' x B1'; drain buf0' stages
        BARRIER(); LGKM0();
        SGB_DS(8); SGB_MFMA(16);
        READ_AF(aa1, 1, 1);
        STAGE_B(1, 0, tn1);
        MM_F(aa0, b1B, 0, 2);
        VMW2();

        // ph7: read next buf0.g0 (drained ph6); stage buf1.B1<-tn1; MM g1' x B1'
        BARRIER(); LGKM0();
        SGB_DS(8); SGB_MFMA(16);
        READ_AF(aa0, 0, 0);
        STAGE_B(1, 1, tn1);
        MM_F(aa1, b1B, 4, 2);

        // ph8: read next buf0.B0; stage buf1.A<-tn1; MM g1' x B0'
        BARRIER(); LGKM0();
        SGB_DS(4); SGB_MFMA(16);
        READ_BF(b0A, 0, 0);
        STAGE_A(1, 0, tn1); STAGE_A(1, 1, tn1);
        MM_F(aa1, b0B, 4, 0);
    }

    // ---- epilogue ----
    float bb[4];
    #pragma unroll
    for (int n = 0; n < 4; ++n)
        bb[n] = (MODE == 3) ? 0.0f : bias[bcol + (wc << 6) + (n << 4) + (lane & 15)];

    const int erow0 = brow + (wr << 7) + ((lane >> 4) << 2);
    const int ecol0 = bcol + (wc << 6) + (lane & 15);

    #pragma unroll
    for (int m = 0; m < 8; ++m) {
        #pragma unroll
        for (int i = 0; i < 4; ++i) {
            const int r = erow0 + (m << 4) + i;
            #pragma unroll
            for (int n = 0; n < 4; ++n) {
                const int c = ecol0 + (n << 4);
                float v = acc[m][n][i] + bb[n];
                if (MODE == 0) {
                    v = v > 0.0f ? v : 0.0f;
                    obf[(size_t)r * N + c] = f2bf_bits(v);
                } else if (MODE == 3) {
                    pp[(size_t)r * N + c] = f2bf_bits(v);
                } else {
                    of32[(size_t)r * N + c] = v;
                }
            }
        }
    }
#undef STAGE_A
#undef STAGE_B
#undef READ_AF
#undef READ_BF
#undef MM_F
}

// ---------- launch ----------
extern "C" void kernel_launch(void* const* d_in, const int* in_sizes, int n_in,
                              void* d_out, int out_size, void* d_ws, size_t ws_size,
                              hipStream_t stream) {
    const float* x   = (const float*)d_in[0];
    const float* We1 = (const float*)d_in[1];
    const float* be1 = (const float*)d_in[2];
    const float* We2 = (const float*)d_in[3];
    const float* be2 = (const float*)d_in[4];
    const float* Wd1 = (const float*)d_in[5];
    const float* bd1 = (const float*)d_in[6];
    const float* Wd2 = (const float*)d_in[7];
    const float* bd2 = (const float*)d_in[8];
    const float* eps = (const float*)d_in[9];

    const int B = 4096, D = 4096, H = 4096, LAT = 512;

    // workspace layout (lifetimes traced):
    //   [0, 33.5M)      xb (dead after G1) -> bf16 partials (4 x 8.39M) -> hd
    //   [33.5M, 67.1M)  w1t (dead after G1)
    //   [67.1M, 75.5M)  w2t  [75.5M, 79.7M) w3t  [79.7M, 113.2M) w4t
    //   [113.2M,146.8M) h (dead after z-GEMM) -> zs at its start
    char* ws = (char*)d_ws;
    u16*   xb    = (u16*)(ws);
    u16*   w1t   = (u16*)(ws + 33554432);
    u16*   w2t   = (u16*)(ws + 67108864);
    u16*   w3t   = (u16*)(ws + 75497472);
    u16*   w4t   = (u16*)(ws + 79691776);
    u16*   h     = (u16*)(ws + 113246208);
    u16*   part  = (u16*)(ws);                  // 4 x (4096x1024) bf16 = 33.5 MB
    u16*   zs    = (u16*)(ws + 113246208);      // over dead h
    u16*   hd    = (u16*)(ws);                  // over dead partials

    float* recon = (float*)d_out;
    float* mu    = recon + (size_t)B * D;
    float* lv    = mu + (size_t)B * LAT;

    hipFuncSetAttribute(reinterpret_cast<const void*>(gemm256<0>),
                        hipFuncAttributeMaxDynamicSharedMemorySize, 131072);
    hipFuncSetAttribute(reinterpret_cast<const void*>(gemm256<1>),
                        hipFuncAttributeMaxDynamicSharedMemorySize, 131072);
    hipFuncSetAttribute(reinterpret_cast<const void*>(gemm256<3>),
                        hipFuncAttributeMaxDynamicSharedMemorySize, 131072);

    // fused preprocessing: 9728 transpose blocks + 16384 cvt blocks
    prep<<<26112, 256, 0, stream>>>(x, xb, We1, w1t, We2, w2t, Wd1, w3t, Wd2, w4t);

    // G1: h = relu(x @ We1 + be1)    M=B, N=H, K=D, 64 tiles
    gemm256<0><<<(B / 256) * (H / 256), 512, 131072, stream>>>(
        xb, w1t, be1, h, nullptr, B, H, D, D / 64);
    // z split-K=4: bf16 partials = h @ We2 (16 tiles per sid)
    gemm256<3><<<(B / 256) * (2 * LAT / 256) * 4, 512, 131072, stream>>>(
        h, w2t, nullptr, part, nullptr, B, 2 * LAT, H, (H / 64) / 4);
    // reduce + bias + sampler
    zred<<<(B * LAT / 4) / 256, 256, 0, stream>>>(part, be2, eps, mu, lv, zs);
    // G3: hd = relu(zs @ Wd1 + bd1)  M=B, N=H, K=LAT, 8 tiles
    gemm256<0><<<(B / 256) * (H / 256), 512, 131072, stream>>>(
        zs, w3t, bd1, hd, nullptr, B, H, LAT, LAT / 64);
    // G5: recon = hd @ Wd2 + bd2     M=B, N=D, K=H, 64 tiles
    gemm256<1><<<(B / 256) * (D / 256), 512, 131072, stream>>>(
        hd, w4t, bd2, nullptr, recon, B, D, H, H / 64);
}

// Round 16
// 346.003 us; speedup vs baseline: 1.2084x; 1.2084x over previous
//
#include <hip/hip_runtime.h>
#include <hip/hip_bf16.h>

typedef __attribute__((ext_vector_type(8))) __bf16 bf16x8;
typedef __attribute__((ext_vector_type(4))) float f32x4;
typedef __attribute__((ext_vector_type(4))) unsigned short ushort4v;
typedef __attribute__((ext_vector_type(8))) unsigned short ushort8v;
typedef unsigned short u16;

// ---------- helpers ----------
__device__ __forceinline__ u16 f2bf_bits(float f) {
    union { float f; unsigned int u; } x; x.f = f;
    unsigned int r = x.u + 0x7FFFu + ((x.u >> 16) & 1u);   // RNE
    return (u16)(r >> 16);
}

__device__ __forceinline__ float bf2f(u16 u) {
    union { unsigned int i; float f; } x; x.i = ((unsigned)u) << 16; return x.f;
}

__device__ __forceinline__ void gload_lds16(const void* g, void* l) {
    __builtin_amdgcn_global_load_lds(
        (const __attribute__((address_space(1))) void*)g,
        (__attribute__((address_space(3))) void*)l, 16, 0, 0);
}

#define BARRIER()  __builtin_amdgcn_s_barrier()
#define LGKM0()    asm volatile("s_waitcnt lgkmcnt(0)" ::: "memory")
#define VMW8()     asm volatile("s_waitcnt vmcnt(8)" ::: "memory")

// ---------- fused preprocessing: x cvt + 4 weight transpose-cvts ----------
__global__ __launch_bounds__(256)
void prep(const float* __restrict__ x,   u16* __restrict__ xb,
          const float* __restrict__ We1, u16* __restrict__ w1t,
          const float* __restrict__ We2, u16* __restrict__ w2t,
          const float* __restrict__ Wd1, u16* __restrict__ w3t,
          const float* __restrict__ Wd2, u16* __restrict__ w4t) {
    int bid = blockIdx.x;

    if (bid >= 9728) {                       // ---- cvt region: x -> xb (16M elems)
        const int i = ((bid - 9728) << 10) + ((int)threadIdx.x << 2);
        f32x4 v = *reinterpret_cast<const f32x4*>(x + i);
        ushort4v o;
        o.x = f2bf_bits(v.x); o.y = f2bf_bits(v.y);
        o.z = f2bf_bits(v.z); o.w = f2bf_bits(v.w);
        *reinterpret_cast<ushort4v*>(xb + i) = o;
        return;
    }

    const float* in; u16* out; int R, C, bx, by;
    if (bid < 4096)      { in = We1; out = w1t; R = 4096; C = 4096; bx = bid & 63; by = bid >> 6; }
    else if (bid < 5120) { bid -= 4096; in = We2; out = w2t; R = 4096; C = 1024; bx = bid & 15; by = bid >> 4; }
    else if (bid < 5632) { bid -= 5120; in = Wd1; out = w3t; R = 512;  C = 4096; bx = bid & 63; by = bid >> 6; }
    else                 { bid -= 5632; in = Wd2; out = w4t; R = 4096; C = 4096; bx = bid & 63; by = bid >> 6; }

    __shared__ float t[64][67];
    const int c0 = bx << 6;
    const int r0 = by << 6;
    const int tx = threadIdx.x & 15;
    const int ty = threadIdx.x >> 4;
    #pragma unroll
    for (int j = 0; j < 4; ++j) {
        f32x4 v = *reinterpret_cast<const f32x4*>(
            &in[(size_t)(r0 + ty + 16 * j) * C + c0 + (tx << 2)]);
        *reinterpret_cast<f32x4*>(&t[ty + 16 * j][tx << 2]) = v;
    }
    __syncthreads();
    const int orow8 = threadIdx.x >> 3;
    const int seg8  = (threadIdx.x & 7) << 3;
    #pragma unroll
    for (int p = 0; p < 2; ++p) {
        const int oc = orow8 + (p << 5);
        ushort8v o;
        #pragma unroll
        for (int i = 0; i < 8; ++i)
            o[i] = f2bf_bits(t[seg8 + i][oc]);
        *reinterpret_cast<ushort8v*>(&out[(size_t)(c0 + oc) * R + r0 + seg8]) = o;
    }
}

// ---------- split-K reduce (bf16 partials) + bias + reparameterization ----------
__global__ __launch_bounds__(256)
void zred(const u16* __restrict__ P, const float* __restrict__ be2,
          const float* __restrict__ eps, float* __restrict__ mu,
          float* __restrict__ lv, u16* __restrict__ zs) {
    const int i = blockIdx.x * 256 + threadIdx.x;      // over 4096*512/4
    const int r = i >> 7;
    const int c4 = (i & 127) << 2;
    const size_t base = (size_t)r * 1024 + c4;
    const size_t PS = (size_t)4096 * 1024;

    f32x4 m = (f32x4)(0.0f);
    f32x4 l = (f32x4)(0.0f);
    #pragma unroll
    for (int s = 0; s < 4; ++s) {
        ushort4v pm = *reinterpret_cast<const ushort4v*>(P + s * PS + base);
        ushort4v pl = *reinterpret_cast<const ushort4v*>(P + s * PS + base + 512);
        m.x += bf2f(pm.x); m.y += bf2f(pm.y); m.z += bf2f(pm.z); m.w += bf2f(pm.w);
        l.x += bf2f(pl.x); l.y += bf2f(pl.y); l.z += bf2f(pl.z); l.w += bf2f(pl.w);
    }
    m += *reinterpret_cast<const f32x4*>(be2 + c4);
    l += *reinterpret_cast<const f32x4*>(be2 + 512 + c4);

    const size_t ob = (size_t)r * 512 + c4;
    *reinterpret_cast<f32x4*>(mu + ob) = m;
    *reinterpret_cast<f32x4*>(lv + ob) = l;

    f32x4 e = *reinterpret_cast<const f32x4*>(eps + ob);
    ushort4v o;
    o.x = f2bf_bits(m.x + __expf(0.5f * l.x) * e.x);
    o.y = f2bf_bits(m.y + __expf(0.5f * l.y) * e.y);
    o.z = f2bf_bits(m.z + __expf(0.5f * l.z) * e.z);
    o.w = f2bf_bits(m.w + __expf(0.5f * l.w) * e.w);
    *reinterpret_cast<ushort4v*>(zs + ob) = o;
}

// ---------- 256x256 8-phase GEMM, single-barrier phases (r9 schedule, 16x16x32) ----------
// MODE 0: relu->bf16 obf. MODE 1: f32 of32. MODE 3: split-K bf16 partial
// (written to obf + sid*M*N), no bias.
template<int MODE>
__global__ __launch_bounds__(512, 2)
void gemm256(const u16* __restrict__ A, const u16* __restrict__ Bt,
             const float* __restrict__ bias,
             u16* __restrict__ obf, float* __restrict__ of32,
             int M, int N, int K, int ntiles)
{
    extern __shared__ char lds[];
    const int tid  = threadIdx.x;
    const int lane = tid & 63;
    const int w    = tid >> 6;
    const int wr   = w >> 2;
    const int wc   = w & 3;

    int bid = blockIdx.x;
    int sid = 0;
    int nwg = gridDim.x;
    if (MODE == 3) { sid = bid & 3; bid >>= 2; nwg >>= 2; }
    const int cpx = nwg >> 3;
    bid = (bid & 7) * cpx + (bid >> 3);
    const int nbx  = N >> 8;
    const int brow = (bid / nbx) << 8;
    const int bcol = (bid % nbx) << 8;
    const int kbase = (MODE == 3) ? sid * ntiles : 0;
    u16* pp = (MODE == 3) ? obf + (size_t)sid * M * N : obf;

    const int srow  = tid >> 3;
    const int scole = (((tid & 7) ^ (srow & 7)) << 4) >> 1;
    const size_t aoff = (size_t)(brow + srow) * K + scole;
    const size_t boff = (size_t)(bcol + srow) * K + scole;
    const size_t rowK64 = (size_t)64 * K;
    const int wave1024 = w << 10;

    const int lo16 = (lane >> 4) << 4;
    const int swzm = (lane & 7) << 4;
    const int low0 = lo16 ^ swzm;
    const int low1 = (64 | lo16) ^ swzm;
    const int rA   = (lane & 15) << 7;
    const int rB   = ((((wc & 1) << 6) | (lane & 15)) << 7);
    const int regA = wr << 14;
    const int regB = 32768 + ((wc >> 1) << 14);

    bf16x8 a[4][2];
    bf16x8 b0[2][2];
    bf16x8 b1[2][2];
    f32x4 acc[8][4];
    #pragma unroll
    for (int m = 0; m < 8; ++m)
        #pragma unroll
        for (int n = 0; n < 4; ++n)
            acc[m][n] = (f32x4)(0.0f);

#define STAGE_A(buf, h, kt) do { \
    const u16* _s = A + aoff + (size_t)(h) * 128 * K + (size_t)(kt) * 64; \
    gload_lds16(_s,          lds + ((buf) << 16) + ((h) << 14) + wave1024); \
    gload_lds16(_s + rowK64, lds + ((buf) << 16) + ((h) << 14) + 8192 + wave1024); \
} while (0)

#define STAGE_B(buf, h, kt) do { \
    const u16* _s = Bt + boff + (size_t)(h) * 128 * K + (size_t)(kt) * 64; \
    gload_lds16(_s,          lds + ((buf) << 16) + 32768 + ((h) << 14) + wave1024); \
    gload_lds16(_s + rowK64, lds + ((buf) << 16) + 32768 + ((h) << 14) + 8192 + wave1024); \
} while (0)

#define READ_A(buf, g) do { \
    _Pragma("unroll") \
    for (int m = 0; m < 4; ++m) { \
        const int _b = ((buf) << 16) + regA + rA + ((((g) << 2) + m) << 11); \
        a[m][0] = *reinterpret_cast<const bf16x8*>(lds + _b + low0); \
        a[m][1] = *reinterpret_cast<const bf16x8*>(lds + _b + low1); \
    } \
} while (0)

#define READ_B0(buf) do { \
    _Pragma("unroll") \
    for (int n = 0; n < 2; ++n) { \
        const int _b = ((buf) << 16) + regB + rB + (n << 11); \
        b0[n][0] = *reinterpret_cast<const bf16x8*>(lds + _b + low0); \
        b0[n][1] = *reinterpret_cast<const bf16x8*>(lds + _b + low1); \
    } \
} while (0)

#define READ_B1(buf) do { \
    _Pragma("unroll") \
    for (int n = 0; n < 2; ++n) { \
        const int _b = ((buf) << 16) + regB + rB + ((n + 2) << 11); \
        b1[n][0] = *reinterpret_cast<const bf16x8*>(lds + _b + low0); \
        b1[n][1] = *reinterpret_cast<const bf16x8*>(lds + _b + low1); \
    } \
} while (0)

#define MM(bx, mb, nb) do { \
    __builtin_amdgcn_s_setprio(1); \
    _Pragma("unroll") \
    for (int m = 0; m < 4; ++m) \
        _Pragma("unroll") \
        for (int n = 0; n < 2; ++n) \
            _Pragma("unroll") \
            for (int s = 0; s < 2; ++s) \
                acc[(mb) + m][(nb) + n] = __builtin_amdgcn_mfma_f32_16x16x32_bf16( \
                    a[m][s], bx[n][s], acc[(mb) + m][(nb) + n], 0, 0, 0); \
    __builtin_amdgcn_s_setprio(0); \
} while (0)

    const int NIT = ntiles >> 1;   // 2 K-tiles of 64 per iteration

    // ---- prologue: tile kbase -> buf0, kbase+1 -> buf1 ----
    STAGE_A(0, 0, kbase); STAGE_A(0, 1, kbase); STAGE_B(0, 0, kbase); STAGE_B(0, 1, kbase);
    STAGE_A(1, 0, kbase + 1); STAGE_A(1, 1, kbase + 1); STAGE_B(1, 0, kbase + 1); STAGE_B(1, 1, kbase + 1);
    VMW8(); BARRIER();
    READ_A(0, 0); READ_B0(0);          // ph1 operands

    for (int it = 0; it < NIT; ++it) {
        const int tn0r = 2 * it + 2;
        const int tn1r = 2 * it + 3;
        const int tn0 = kbase + (tn0r < ntiles ? tn0r : ntiles - 1);  // dead-stage clamp
        const int tn1 = kbase + (tn1r < ntiles ? tn1r : ntiles - 1);

        // ph1
        BARRIER(); LGKM0();
        MM(b0, 0, 0);
        READ_B1(0);

        // ph2
        BARRIER(); LGKM0();
        STAGE_B(0, 0, tn0);            // B0 last read-issue: prev ph8
        MM(b1, 0, 2);
        READ_A(0, 1);

        // ph3
        BARRIER(); LGKM0();
        STAGE_B(0, 1, tn0);            // B1 last read-issue: ph1
        MM(b1, 4, 2);

        // ph4
        BARRIER(); LGKM0();
        STAGE_A(0, 0, tn0); STAGE_A(0, 1, tn0);  // A last read-issue: ph2
        MM(b0, 4, 0);
        VMW8();                        // drains prev-iter buf1 stages (lead 4 phases)
        READ_A(1, 0); READ_B0(1);

        // ph5
        BARRIER(); LGKM0();
        MM(b0, 0, 0);
        READ_B1(1);

        // ph6
        BARRIER(); LGKM0();
        STAGE_B(1, 0, tn1);
        MM(b1, 0, 2);
        READ_A(1, 1);

        // ph7
        BARRIER(); LGKM0();
        STAGE_B(1, 1, tn1);
        MM(b1, 4, 2);

        // ph8
        BARRIER(); LGKM0();
        STAGE_A(1, 0, tn1); STAGE_A(1, 1, tn1);
        MM(b0, 4, 0);
        VMW8();                        // drains this-iter buf0 stages (lead 4 phases)
        READ_A(0, 0); READ_B0(0);
    }

    // ---- epilogue ----
    float bb[4];
    #pragma unroll
    for (int n = 0; n < 4; ++n)
        bb[n] = (MODE == 3) ? 0.0f : bias[bcol + (wc << 6) + (n << 4) + (lane & 15)];

    const int erow0 = brow + (wr << 7) + ((lane >> 4) << 2);
    const int ecol0 = bcol + (wc << 6) + (lane & 15);

    #pragma unroll
    for (int m = 0; m < 8; ++m) {
        #pragma unroll
        for (int i = 0; i < 4; ++i) {
            const int r = erow0 + (m << 4) + i;
            #pragma unroll
            for (int n = 0; n < 4; ++n) {
                const int c = ecol0 + (n << 4);
                float v = acc[m][n][i] + bb[n];
                if (MODE == 0) {
                    v = v > 0.0f ? v : 0.0f;
                    obf[(size_t)r * N + c] = f2bf_bits(v);
                } else if (MODE == 3) {
                    pp[(size_t)r * N + c] = f2bf_bits(v);
                } else {
                    of32[(size_t)r * N + c] = v;
                }
            }
        }
    }
#undef STAGE_A
#undef STAGE_B
#undef READ_A
#undef READ_B0
#undef READ_B1
#undef MM
}

// ---------- launch ----------
extern "C" void kernel_launch(void* const* d_in, const int* in_sizes, int n_in,
                              void* d_out, int out_size, void* d_ws, size_t ws_size,
                              hipStream_t stream) {
    const float* x   = (const float*)d_in[0];
    const float* We1 = (const float*)d_in[1];
    const float* be1 = (const float*)d_in[2];
    const float* We2 = (const float*)d_in[3];
    const float* be2 = (const float*)d_in[4];
    const float* Wd1 = (const float*)d_in[5];
    const float* bd1 = (const float*)d_in[6];
    const float* Wd2 = (const float*)d_in[7];
    const float* bd2 = (const float*)d_in[8];
    const float* eps = (const float*)d_in[9];

    const int B = 4096, D = 4096, H = 4096, LAT = 512;

    // workspace layout (lifetimes traced):
    //   [0, 33.5M)      xb (dead after G1) -> bf16 partials (4 x 8.39M) -> hd
    //   [33.5M, 67.1M)  w1t (dead after G1)
    //   [67.1M, 75.5M)  w2t  [75.5M, 79.7M) w3t  [79.7M, 113.2M) w4t
    //   [113.2M,146.8M) h (dead after z-GEMM) -> zs at its start
    char* ws = (char*)d_ws;
    u16*   xb    = (u16*)(ws);
    u16*   w1t   = (u16*)(ws + 33554432);
    u16*   w2t   = (u16*)(ws + 67108864);
    u16*   w3t   = (u16*)(ws + 75497472);
    u16*   w4t   = (u16*)(ws + 79691776);
    u16*   h     = (u16*)(ws + 113246208);
    u16*   part  = (u16*)(ws);                  // 4 x (4096x1024) bf16 = 33.5 MB
    u16*   zs    = (u16*)(ws + 113246208);      // over dead h
    u16*   hd    = (u16*)(ws);                  // over dead partials

    float* recon = (float*)d_out;
    float* mu    = recon + (size_t)B * D;
    float* lv    = mu + (size_t)B * LAT;

    hipFuncSetAttribute(reinterpret_cast<const void*>(gemm256<0>),
                        hipFuncAttributeMaxDynamicSharedMemorySize, 131072);
    hipFuncSetAttribute(reinterpret_cast<const void*>(gemm256<1>),
                        hipFuncAttributeMaxDynamicSharedMemorySize, 131072);
    hipFuncSetAttribute(reinterpret_cast<const void*>(gemm256<3>),
                        hipFuncAttributeMaxDynamicSharedMemorySize, 131072);

    // fused preprocessing: 9728 transpose blocks + 16384 cvt blocks
    prep<<<26112, 256, 0, stream>>>(x, xb, We1, w1t, We2, w2t, Wd1, w3t, Wd2, w4t);

    // G1: h = relu(x @ We1 + be1)    M=B, N=H, K=D, 64 tiles
    gemm256<0><<<(B / 256) * (H / 256), 512, 131072, stream>>>(
        xb, w1t, be1, h, nullptr, B, H, D, D / 64);
    // z split-K=4: bf16 partials = h @ We2 (16 tiles per sid)
    gemm256<3><<<(B / 256) * (2 * LAT / 256) * 4, 512, 131072, stream>>>(
        h, w2t, nullptr, part, nullptr, B, 2 * LAT, H, (H / 64) / 4);
    // reduce + bias + sampler
    zred<<<(B * LAT / 4) / 256, 256, 0, stream>>>(part, be2, eps, mu, lv, zs);
    // G3: hd = relu(zs @ Wd1 + bd1)  M=B, N=H, K=LAT, 8 tiles
    gemm256<0><<<(B / 256) * (H / 256), 512, 131072, stream>>>(
        zs, w3t, bd1, hd, nullptr, B, H, LAT, LAT / 64);
    // G5: recon = hd @ Wd2 + bd2     M=B, N=D, K=H, 64 tiles
    gemm256<1><<<(B / 256) * (D / 256), 512, 131072, stream>>>(
        hd, w4t, bd2, nullptr, recon, B, D, H, H / 64);
}